// Round 1
// baseline (3192.371 us; speedup 1.0000x reference)
//
#include <hip/hip_runtime.h>
#include <math.h>

#define B_   2
#define N_   4096
#define V_   32768
#define K_   128
#define S_   32
#define CH   3
#define NEPS 12

#define LOG2E 1.4426950408889634f
#define LN2   0.6931471805599453f

__constant__ float c_eps[NEPS] = {4.0f, 1.0f, 0.25f, 0.0625f, 0.015625f, 0.00390625f,
                                  0.0025f, 0.0025f, 0.0025f, 0.0025f, 0.0025f, 0.0025f};

__device__ __forceinline__ float fexp2(float x) {
#if __has_builtin(__builtin_amdgcn_exp2f)
  return __builtin_amdgcn_exp2f(x);
#else
  return exp2f(x);
#endif
}
__device__ __forceinline__ float flog2(float x) {
#if __has_builtin(__builtin_amdgcn_logf)
  return __builtin_amdgcn_logf(x);
#else
  return log2f(x);
#endif
}

// ---- static device scratch (avoids any dependence on ws_size) ----
__device__ float4 g_P [B_*N_];          // {x,y,z, 0.5|x|^2}
__device__ float4 g_U [B_*N_];          // per-iteration transformed h (3 channels)
__device__ float  g_alog[B_*CH*N_];     // [b][c][n] natural log of w
__device__ float  g_fa  [B_*CH*N_];     // sym potentials (x side)
__device__ float  g_Fa  [B_*CH*N_];     // final F_a
__device__ float2 g_part[S_*CH*B_*N_];  // [(s*CH+c)][b*N+n] partial (max,sum)
__device__ float4 g_pts [B_*CH*K_];     // {p,0.5|p|^2}
__device__ float  g_blog[B_*CH*K_];
__device__ float  g_bval[B_*CH*K_];
__device__ float  g_S1[6];
__device__ float  g_S2[6];

// online logsumexp update in base-2 domain
__device__ __forceinline__ void lse_up(float t, float& m, float& s) {
  if (t > m) { s = s * fexp2(m - t) + 1.0f; m = t; }
  else       { s += fexp2(t - m); }
}

// ================= top-K (6 rows, exact jax.lax.top_k semantics) =================
__global__ __launch_bounds__(1024) void k_topk(const float* __restrict__ yhat,
                                               const float* __restrict__ vox) {
  const int bc  = blockIdx.x;            // b*3+c
  const int tid = threadIdx.x;
  const float* row = yhat + (size_t)bc * V_;
  float v[32];
#pragma unroll
  for (int j = 0; j < 32; ++j) v[j] = row[tid + j * 1024];

  __shared__ int s_cnt;
  unsigned lo = 0u, hi = 0x3f800000u;    // values in [0,1)
  while (lo < hi) {
    unsigned mid = lo + ((hi - lo + 1u) >> 1);
    if (tid == 0) s_cnt = 0;
    __syncthreads();
    int local = 0;
#pragma unroll
    for (int j = 0; j < 32; ++j) local += (__float_as_uint(v[j]) >= mid) ? 1 : 0;
    if (local) atomicAdd(&s_cnt, local);
    __syncthreads();
    int cnt = s_cnt;
    __syncthreads();
    if (cnt >= K_) lo = mid; else hi = mid - 1u;
  }
  const unsigned T = lo;                 // bits of the K-th largest value

  if (tid == 0) s_cnt = 0;
  __syncthreads();
  {
    int local = 0;
#pragma unroll
    for (int j = 0; j < 32; ++j) local += (__float_as_uint(v[j]) > T) ? 1 : 0;
    if (local) atomicAdd(&s_cnt, local);
  }
  __syncthreads();
  const int c1 = s_cnt;                  // strictly greater count (< K)
  __syncthreads();

  __shared__ int   s_pos, s_eq;
  __shared__ float s_vals[K_];
  __shared__ int   s_idx[K_];
  __shared__ int   s_eqi[1024];
  if (tid == 0) { s_pos = 0; s_eq = 0; }
  __syncthreads();
#pragma unroll
  for (int j = 0; j < 32; ++j) {
    unsigned bt = __float_as_uint(v[j]);
    int i = tid + j * 1024;
    if (bt > T) {
      int p = atomicAdd(&s_pos, 1);
      s_vals[p] = v[j]; s_idx[p] = i;
    } else if (bt == T) {
      int p = atomicAdd(&s_eq, 1);
      if (p < 1024) s_eqi[p] = i;
    }
  }
  __syncthreads();
  const int ec   = min(s_eq, 1024);
  const int need = K_ - c1;
  for (int e = tid; e < ec; e += 1024) { // ties: smallest indices win
    int my = s_eqi[e];
    int rank = 0;
    for (int j2 = 0; j2 < ec; ++j2) rank += (s_eqi[j2] < my) ? 1 : 0;
    if (rank < need) { s_vals[c1 + rank] = __uint_as_float(T); s_idx[c1 + rank] = my; }
  }
  __syncthreads();
  if (tid < K_) {                        // deterministic (val desc, idx asc) order
    float mv = s_vals[tid]; int mi = s_idx[tid];
    int rank = 0;
    for (int j2 = 0; j2 < K_; ++j2) {
      float ov = s_vals[j2]; int oi = s_idx[j2];
      rank += ((ov > mv) || (ov == mv && oi < mi)) ? 1 : 0;
    }
    float p0 = vox[(size_t)mi * 3 + 0];
    float p1 = vox[(size_t)mi * 3 + 1];
    float p2 = vox[(size_t)mi * 3 + 2];
    g_pts [bc * K_ + rank] = make_float4(p0, p1, p2, 0.5f * (p0*p0 + p1*p1 + p2*p2));
    g_bval[bc * K_ + rank] = mv;
    g_blog[bc * K_ + rank] = flog2(fmaxf(mv, 1e-20f)) * LN2;
  }
}

// ================= prep: pack xyz + norms, a_log, init fa/U =================
__global__ __launch_bounds__(256) void k_prep(const float* __restrict__ y) {
  const int idx = blockIdx.x * 256 + threadIdx.x;  // b*N+n
  const int b = idx / N_, n = idx % N_;
  const float* yr = y + (size_t)idx * 6;
  float x0 = yr[0], x1 = yr[1], x2 = yr[2];
  float q0 = 0.5f * (x0*x0 + x1*x1 + x2*x2);
  g_P[idx] = make_float4(x0, x1, x2, q0);
  float U[CH];
#pragma unroll
  for (int c = 0; c < CH; ++c) {
    float w  = yr[3 + c];
    float al = flog2(fmaxf(w, 1e-20f)) * LN2;
    g_alog[(b*CH + c)*N_ + n] = al;
    g_fa  [(b*CH + c)*N_ + n] = 0.f;
    U[c] = LOG2E * al;                    // fa=0 -> U = log2e * a_log
  }
  g_U[idx] = make_float4(U[0], U[1], U[2], 0.f);
}

// ================= big symmetric pass over C_xx (partial LSE) =================
__global__ __launch_bounds__(256) void k_xx_pass(float eps) {
  const int nb = blockIdx.x;               // 0..31
  const int s  = blockIdx.y;               // 0..31
  const int b  = nb >> 4;
  const int tid = threadIdx.x;
  const int n  = ((nb & 15) << 8) + tid;
  const int m0 = s << 7;
  const float il = LOG2E / eps;
  __shared__ float4 s_p[128];
  __shared__ float4 s_u[128];
  float4 Pn = g_P[b*N_ + n];
  if (tid < 128) s_p[tid]        = g_P[b*N_ + m0 + tid];
  else           s_u[tid - 128]  = g_U[b*N_ + m0 + (tid - 128)];
  __syncthreads();
  const float xn0 = Pn.x, xn1 = Pn.y, xn2 = Pn.z, q0n = Pn.w;
  float M0 = -INFINITY, M1 = -INFINITY, M2 = -INFINITY;
  float s0 = 0.f, s1 = 0.f, s2 = 0.f;
#pragma unroll 4
  for (int m = 0; m < 128; ++m) {
    float4 pm = s_p[m];
    float4 um = s_u[m];
    float dot = xn0*pm.x + xn1*pm.y + xn2*pm.z;
    float C   = fmaxf(q0n + pm.w - dot, 0.f);   // = 0.5*sqdist, clamped like ref
    float nC  = -C * il;
    lse_up(um.x + nC, M0, s0);
    lse_up(um.y + nC, M1, s1);
    lse_up(um.z + nC, M2, s2);
  }
  const int bn = b*N_ + n;
  g_part[(s*CH + 0)*(B_*N_) + bn] = make_float2(M0, s0);
  g_part[(s*CH + 1)*(B_*N_) + bn] = make_float2(M1, s1);
  g_part[(s*CH + 2)*(B_*N_) + bn] = make_float2(M2, s2);
}

// merge partials; mode 0: fa update + next-iteration U; mode 1: write F_a
__global__ __launch_bounds__(256) void k_xx_combine(float eps_cur, float eps_next, int mode) {
  const int idx = blockIdx.x * 256 + threadIdx.x;  // b*N+n
  const int b = idx / N_, n = idx % N_;
  float M[CH] = {-INFINITY, -INFINITY, -INFINITY};
  float S[CH] = {0.f, 0.f, 0.f};
  for (int s = 0; s < S_; ++s) {
#pragma unroll
    for (int c = 0; c < CH; ++c) {
      float2 p = g_part[(s*CH + c)*(B_*N_) + idx];
      if (p.x > M[c]) { S[c] = S[c] * fexp2(M[c] - p.x) + p.y; M[c] = p.x; }
      else            { S[c] += p.y * fexp2(p.x - M[c]); }
    }
  }
  const float iln = LOG2E / eps_next;
  float U[CH];
#pragma unroll
  for (int c = 0; c < CH; ++c) {
    float sm = -eps_cur * LN2 * (M[c] + flog2(S[c]));
    int o = (b*CH + c)*N_ + n;
    if (mode == 0) {
      float fn = 0.5f * (g_fa[o] + sm);
      g_fa[o] = fn;
      U[c] = fmaf(fn, iln, LOG2E * g_alog[o]);
    } else {
      g_Fa[o] = sm;
      U[c] = 0.f;
    }
  }
  if (mode == 0) g_U[idx] = make_float4(U[0], U[1], U[2], 0.f);
}

// ================= yy loop (K x K, fully block-local) =================
__global__ __launch_bounds__(128) void k_yy() {
  const int bc = blockIdx.x;
  const int k  = threadIdx.x;
  __shared__ float4 s_pt[K_];
  __shared__ float  s_hm[K_];
  __shared__ float  s_red[2];
  float4 Pk = g_pts[bc*K_ + k];
  s_pt[k] = Pk;
  const float blogk = g_blog[bc*K_ + k];
  float g = 0.f;
  __syncthreads();
  for (int it = 0; it < NEPS; ++it) {
    const float eps = c_eps[it];
    const float il  = LOG2E / eps;
    s_hm[k] = fmaf(g, il, LOG2E * blogk);
    __syncthreads();
    float M = -INFINITY, Ss = 0.f;
    for (int m = 0; m < K_; ++m) {
      float4 pm = s_pt[m];
      float dot = Pk.x*pm.x + Pk.y*pm.y + Pk.z*pm.z;
      float C   = fmaxf(Pk.w + pm.w - dot, 0.f);
      lse_up(s_hm[m] - C*il, M, Ss);
    }
    float gt = -eps * LN2 * (M + flog2(Ss));
    g = 0.5f * (g + gt);
    __syncthreads();
  }
  { // final G_b with eps_last, then S2 = sum_k b*G_b
    const float eps = 0.0025f, il = LOG2E / eps;
    s_hm[k] = fmaf(g, il, LOG2E * blogk);
    __syncthreads();
    float M = -INFINITY, Ss = 0.f;
    for (int m = 0; m < K_; ++m) {
      float4 pm = s_pt[m];
      float dot = Pk.x*pm.x + Pk.y*pm.y + Pk.z*pm.z;
      float C   = fmaxf(Pk.w + pm.w - dot, 0.f);
      lse_up(s_hm[m] - C*il, M, Ss);
    }
    float Gb = -eps * LN2 * (M + flog2(Ss));
    float local = g_bval[bc*K_ + k] * Gb;
    for (int off = 32; off; off >>= 1) local += __shfl_down(local, off);
    if ((threadIdx.x & 63) == 0) s_red[threadIdx.x >> 6] = local;
    __syncthreads();
    if (threadIdx.x == 0) g_S2[bc] = s_red[0] + s_red[1];
  }
}

// ================= ab loop (N x K, fully block-local per (b,c)) =================
__global__ __launch_bounds__(1024) void k_ab(const float* __restrict__ y) {
  const int bc = blockIdx.x; const int b = bc / 3, c = bc % 3;
  const int tid = threadIdx.x;
  __shared__ float4 s_pt[K_];
  __shared__ float  s_hk[K_];
  __shared__ float  s_g[K_];
  __shared__ float  s_hn[N_];
  __shared__ float  s_f[N_];
  __shared__ float2 s_gp[K_][8];
  __shared__ float  s_red[16];

  if (tid < K_) { s_pt[tid] = g_pts[bc*K_ + tid]; s_g[tid] = 0.f; }
  float4 Pn[4]; float al[4]; float av[4];
#pragma unroll
  for (int j = 0; j < 4; ++j) {
    int n = tid + j * 1024;
    Pn[j] = g_P[b*N_ + n];
    al[j] = g_alog[(b*CH + c)*N_ + n];
    av[j] = y[((size_t)(b*N_ + n)) * 6 + 3 + c];
    s_f[n] = 0.f;
  }
  const float blogk_t = (tid < K_) ? g_blog[bc*K_ + tid] : 0.f;
  __syncthreads();

  const int kk   = tid & (K_ - 1);
  const int part = tid >> 7;             // 0..7
  const float4 Pk = s_pt[kk];

  for (int it = 0; it < NEPS; ++it) {
    const float eps = c_eps[it];
    const float il  = LOG2E / eps;
#pragma unroll
    for (int j = 0; j < 4; ++j) {
      int n = tid + j * 1024;
      s_hn[n] = fmaf(s_f[n], il, LOG2E * al[j]);
    }
    if (tid < K_) s_hk[tid] = fmaf(s_g[tid], il, LOG2E * blogk_t);
    __syncthreads();
    // ft over own n's (Jacobi: uses snapshot hk)
#pragma unroll
    for (int j = 0; j < 4; ++j) {
      int n = tid + j * 1024;
      float M = -INFINITY, Ss = 0.f;
      const float q0n = Pn[j].w;
      for (int k2 = 0; k2 < K_; ++k2) {
        float4 pm = s_pt[k2];
        float dot = Pn[j].x*pm.x + Pn[j].y*pm.y + Pn[j].z*pm.z;
        float C   = fmaxf(q0n + pm.w - dot, 0.f);
        lse_up(s_hk[k2] - C*il, M, Ss);
      }
      float ftv = -eps * LN2 * (M + flog2(Ss));
      s_f[n] = 0.5f * (s_f[n] + ftv);    // safe: only owner touches s_f[n]; gt uses s_hn
    }
    // gt partials over n-range (uses snapshot hn)
    {
      float M = -INFINITY, Ss = 0.f;
      const int nlo = part * (N_ / 8);
      for (int n2 = nlo; n2 < nlo + N_/8; ++n2) {
        float4 xm = g_P[b*N_ + n2];
        float dot = Pk.x*xm.x + Pk.y*xm.y + Pk.z*xm.z;
        float C   = fmaxf(Pk.w + xm.w - dot, 0.f);
        lse_up(s_hn[n2] - C*il, M, Ss);
      }
      s_gp[kk][part] = make_float2(M, Ss);
    }
    __syncthreads();
    if (tid < K_) {
      float M = -INFINITY, Ss = 0.f;
#pragma unroll
      for (int p = 0; p < 8; ++p) {
        float2 q = s_gp[tid][p];
        if (q.x > M) { Ss = Ss * fexp2(M - q.x) + q.y; M = q.x; }
        else         { Ss += q.y * fexp2(q.x - M); }
      }
      float gtv = -eps * LN2 * (M + flog2(Ss));
      s_g[tid] = 0.5f * (s_g[tid] + gtv);
    }
    __syncthreads();
  }

  // final F_ab / G_ab with eps_last, reduce S1 = sum_n a*F_ab + sum_k b*G_ab
  const float eps = 0.0025f, il = LOG2E / eps;
#pragma unroll
  for (int j = 0; j < 4; ++j) { int n = tid + j*1024; s_hn[n] = fmaf(s_f[n], il, LOG2E * al[j]); }
  if (tid < K_) s_hk[tid] = fmaf(s_g[tid], il, LOG2E * blogk_t);
  __syncthreads();
  float accA = 0.f;
#pragma unroll
  for (int j = 0; j < 4; ++j) {
    int n = tid + j * 1024;
    float M = -INFINITY, Ss = 0.f;
    const float q0n = Pn[j].w;
    for (int k2 = 0; k2 < K_; ++k2) {
      float4 pm = s_pt[k2];
      float dot = Pn[j].x*pm.x + Pn[j].y*pm.y + Pn[j].z*pm.z;
      float C   = fmaxf(q0n + pm.w - dot, 0.f);
      lse_up(s_hk[k2] - C*il, M, Ss);
    }
    float Fab = -eps * LN2 * (M + flog2(Ss));
    accA += av[j] * Fab;
  }
  {
    float M = -INFINITY, Ss = 0.f;
    const int nlo = part * (N_ / 8);
    for (int n2 = nlo; n2 < nlo + N_/8; ++n2) {
      float4 xm = g_P[b*N_ + n2];
      float dot = Pk.x*xm.x + Pk.y*xm.y + Pk.z*xm.z;
      float C   = fmaxf(Pk.w + xm.w - dot, 0.f);
      lse_up(s_hn[n2] - C*il, M, Ss);
    }
    s_gp[kk][part] = make_float2(M, Ss);
  }
  __syncthreads();
  float accB = 0.f;
  if (tid < K_) {
    float M = -INFINITY, Ss = 0.f;
#pragma unroll
    for (int p = 0; p < 8; ++p) {
      float2 q = s_gp[tid][p];
      if (q.x > M) { Ss = Ss * fexp2(M - q.x) + q.y; M = q.x; }
      else         { Ss += q.y * fexp2(q.x - M); }
    }
    float Gab = -eps * LN2 * (M + flog2(Ss));
    accB = g_bval[bc*K_ + tid] * Gab;
  }
  float val = accA + accB;
  for (int off = 32; off; off >>= 1) val += __shfl_down(val, off);
  if ((tid & 63) == 0) s_red[tid >> 6] = val;
  __syncthreads();
  if (tid == 0) {
    float t = 0.f;
#pragma unroll
    for (int i = 0; i < 16; ++i) t += s_red[i];
    g_S1[bc] = t;
  }
}

// ================= finalize: total = sum(S1 - S2) - sum a*F_a =================
__global__ __launch_bounds__(1024) void k_final(const float* __restrict__ y,
                                                float* __restrict__ out) {
  const int tid = threadIdx.x;
  float local = 0.f;
  for (int i = tid; i < B_*CH*N_; i += 1024) {
    int b = i / (CH*N_); int r = i - b*CH*N_; int c = r / N_; int n = r - c*N_;
    float a = y[((size_t)(b*N_ + n)) * 6 + 3 + c];
    local += a * g_Fa[i];
  }
  for (int off = 32; off; off >>= 1) local += __shfl_down(local, off);
  __shared__ float s_red[16];
  if ((tid & 63) == 0) s_red[tid >> 6] = local;
  __syncthreads();
  if (tid == 0) {
    float t = 0.f;
#pragma unroll
    for (int i = 0; i < 16; ++i) t += s_red[i];
    float tot = -t;
#pragma unroll
    for (int j = 0; j < 6; ++j) tot += g_S1[j] - g_S2[j];
    out[0] = tot;
  }
}

extern "C" void kernel_launch(void* const* d_in, const int* in_sizes, int n_in,
                              void* d_out, int out_size, void* d_ws, size_t ws_size,
                              hipStream_t stream) {
  const float* y_hat = (const float*)d_in[0];
  const float* y     = (const float*)d_in[1];
  const float* vox   = (const float*)d_in[2];
  float* out = (float*)d_out;

  static const float eps_list[NEPS] = {4.0f, 1.0f, 0.25f, 0.0625f, 0.015625f, 0.00390625f,
                                       0.0025f, 0.0025f, 0.0025f, 0.0025f, 0.0025f, 0.0025f};

  k_topk<<<6, 1024, 0, stream>>>(y_hat, vox);
  k_prep<<<(B_*N_)/256, 256, 0, stream>>>(y);
  k_yy<<<6, 128, 0, stream>>>();
  k_ab<<<6, 1024, 0, stream>>>(y);
  for (int it = 0; it < NEPS; ++it) {
    k_xx_pass<<<dim3(32, 32), 256, 0, stream>>>(eps_list[it]);
    float eps_next = (it < NEPS - 1) ? eps_list[it + 1] : 0.0025f;
    k_xx_combine<<<32, 256, 0, stream>>>(eps_list[it], eps_next, 0);
  }
  // one more pass for F_a at eps_last
  k_xx_pass<<<dim3(32, 32), 256, 0, stream>>>(0.0025f);
  k_xx_combine<<<32, 256, 0, stream>>>(0.0025f, 1.0f, 1);
  k_final<<<1, 1024, 0, stream>>>(y, out);
}

// Round 2
// 778.717 us; speedup vs baseline: 4.0995x; 4.0995x over previous
//
#include <hip/hip_runtime.h>
#include <math.h>

#define B_   2
#define N_   4096
#define V_   32768
#define K_   128
#define S_   32
#define CH   3
#define NEPS 12

#define LOG2E 1.4426950408889634f
#define LN2   0.6931471805599453f

__device__ __forceinline__ float fexp2(float x) { return exp2f(x); }
__device__ __forceinline__ float flog2(float x) { return log2f(x); }

// ---- static device scratch ----
__device__ float4 g_P  [B_*N_];          // {x,y,z, 0.5|x|^2}
__device__ float4 g_U4 [B_*N_];          // per-iteration transformed h (3 channels)
__device__ float  g_alog[B_*CH*N_];      // [bc][n] natural log of w
__device__ float  g_fa  [B_*CH*N_];      // sym potentials (x side)
__device__ float  g_Fa  [B_*CH*N_];      // final F_a
__device__ float2 g_part[S_*CH*B_*N_];   // [(s*CH+c)][b*N+n] partial (max,sum)
__device__ float4 g_pts [B_*CH*K_];      // {p, 0.5|p|^2}
__device__ float  g_blog[B_*CH*K_];
__device__ float  g_bval[B_*CH*K_];
__device__ float  g_fbuf[2][B_*CH*N_];   // ping-pong f for ab loop
__device__ float  g_gbuf[2][B_*CH*K_];   // ping-pong g for ab loop
__device__ float  g_S1a[96];             // block partials of sum a*F_ab
__device__ float  g_Gab[768];            // b*G_ab per (bc,k)
__device__ float  g_S2[6];               // sum b*G_b per bc

// branchless online logsumexp update (base-2)
__device__ __forceinline__ void lse_up(float t, float& m, float& s) {
  float mn = fmaxf(m, t);
  float e  = fexp2(-fabsf(t - m));   // exp2(min-max); m=-inf,t finite -> e=0, path ok
  bool  gt = t > m;
  float mulv = gt ? e : 1.0f;
  float addv = gt ? 1.0f : e;
  s = fmaf(s, mulv, addv);
  m = mn;
}
// branchless merge of two (max,sum) pairs
__device__ __forceinline__ void lse_merge(float& M, float& S, float oM, float oS) {
  float mn = fmaxf(M, oM);
  float e  = fexp2(-fabsf(M - oM));
  bool  gt = oM > M;
  float sm = gt ? e : 1.0f;
  float so = gt ? 1.0f : e;
  S = fmaf(S, sm, oS * so);
  M = mn;
}

// ================= top-K (6 rows, jax.lax.top_k semantics) =================
__global__ __launch_bounds__(1024) void k_topk(const float* __restrict__ yhat,
                                               const float* __restrict__ vox) {
  const int bc  = blockIdx.x;            // b*3+c
  const int tid = threadIdx.x;
  const float* row = yhat + (size_t)bc * V_;
  float v[32];
#pragma unroll
  for (int j = 0; j < 32; ++j) v[j] = row[tid + j * 1024];

  if (tid < K_) g_gbuf[0][bc*K_ + tid] = 0.f;   // init ab g potential

  __shared__ int s_cnt;
  unsigned lo = 0u, hi = 0x3f800000u;    // values in [0,1)
  while (lo < hi) {
    unsigned mid = lo + ((hi - lo + 1u) >> 1);
    if (tid == 0) s_cnt = 0;
    __syncthreads();
    int local = 0;
#pragma unroll
    for (int j = 0; j < 32; ++j) local += (__float_as_uint(v[j]) >= mid) ? 1 : 0;
    for (int off = 32; off; off >>= 1) local += __shfl_down(local, off);
    if ((tid & 63) == 0 && local) atomicAdd(&s_cnt, local);
    __syncthreads();
    int cnt = s_cnt;
    __syncthreads();
    if (cnt >= K_) lo = mid; else hi = mid - 1u;
  }
  const unsigned T = lo;                 // bits of the K-th largest value

  if (tid == 0) s_cnt = 0;
  __syncthreads();
  {
    int local = 0;
#pragma unroll
    for (int j = 0; j < 32; ++j) local += (__float_as_uint(v[j]) > T) ? 1 : 0;
    for (int off = 32; off; off >>= 1) local += __shfl_down(local, off);
    if ((tid & 63) == 0 && local) atomicAdd(&s_cnt, local);
  }
  __syncthreads();
  const int c1 = s_cnt;                  // strictly-greater count (< K)
  __syncthreads();

  __shared__ int   s_pos, s_eq;
  __shared__ float s_vals[K_];
  __shared__ int   s_idx[K_];
  __shared__ int   s_eqi[1024];
  if (tid == 0) { s_pos = 0; s_eq = 0; }
  __syncthreads();
#pragma unroll
  for (int j = 0; j < 32; ++j) {
    unsigned bt = __float_as_uint(v[j]);
    int i = tid + j * 1024;
    if (bt > T) {
      int p = atomicAdd(&s_pos, 1);
      s_vals[p] = v[j]; s_idx[p] = i;
    } else if (bt == T) {
      int p = atomicAdd(&s_eq, 1);
      if (p < 1024) s_eqi[p] = i;
    }
  }
  __syncthreads();
  const int ec   = min(s_eq, 1024);
  const int need = K_ - c1;
  for (int e = tid; e < ec; e += 1024) { // ties: smallest indices win
    int my = s_eqi[e];
    int rank = 0;
    for (int j2 = 0; j2 < ec; ++j2) rank += (s_eqi[j2] < my) ? 1 : 0;
    if (rank < need) { s_vals[c1 + rank] = __uint_as_float(T); s_idx[c1 + rank] = my; }
  }
  __syncthreads();
  if (tid < K_) {                        // deterministic (val desc, idx asc) order
    float mv = s_vals[tid]; int mi = s_idx[tid];
    int rank = 0;
    for (int j2 = 0; j2 < K_; ++j2) {
      float ov = s_vals[j2]; int oi = s_idx[j2];
      rank += ((ov > mv) || (ov == mv && oi < mi)) ? 1 : 0;
    }
    float p0 = vox[(size_t)mi * 3 + 0];
    float p1 = vox[(size_t)mi * 3 + 1];
    float p2 = vox[(size_t)mi * 3 + 2];
    g_pts [bc * K_ + rank] = make_float4(p0, p1, p2, 0.5f * (p0*p0 + p1*p1 + p2*p2));
    g_bval[bc * K_ + rank] = mv;
    g_blog[bc * K_ + rank] = flog2(fmaxf(mv, 1e-20f)) * LN2;
  }
}

// ================= prep =================
__global__ __launch_bounds__(256) void k_prep(const float* __restrict__ y) {
  const int idx = blockIdx.x * 256 + threadIdx.x;  // b*N+n
  const int b = idx >> 12, n = idx & (N_ - 1);
  const float* yr = y + (size_t)idx * 6;
  float x0 = yr[0], x1 = yr[1], x2 = yr[2];
  float q0 = 0.5f * (x0*x0 + x1*x1 + x2*x2);
  g_P[idx] = make_float4(x0, x1, x2, q0);
  float U[CH];
#pragma unroll
  for (int c = 0; c < CH; ++c) {
    float w  = yr[3 + c];
    float al = flog2(fmaxf(w, 1e-20f)) * LN2;
    const int o = (b*CH + c)*N_ + n;
    g_alog[o] = al;
    g_fa  [o] = 0.f;
    g_fbuf[0][o] = 0.f;
    U[c] = LOG2E * al;
  }
  g_U4[idx] = make_float4(U[0], U[1], U[2], 0.f);
}

// ======== fused pass: xx partial-LSE (blocks 0..1023) + ab ft (96) + ab gt (192) ========
__global__ __launch_bounds__(256) void k_pass(float eps, int mode, int src,
                                              const float* __restrict__ y) {
  const float il = LOG2E / eps, nil = -il;
  const int blk = blockIdx.x, tid = threadIdx.x;
  __shared__ float4 s_p[128];
  __shared__ float4 s_u[128];
  __shared__ float  s_hk[K_];
  __shared__ float  s_red[4];

  if (blk < 1024) {
    // ---- xx part: n-chunk 256 x m-chunk 128 ----
    const int nb = blk & 31, s = blk >> 5;
    const int b  = nb >> 4;
    const int n  = ((nb & 15) << 8) + tid;
    const int m0 = s << 7;
    if (tid < 128) s_p[tid]       = g_P [b*N_ + m0 + tid];
    else           s_u[tid - 128] = g_U4[b*N_ + m0 + (tid - 128)];
    float4 Pn = g_P[b*N_ + n];
    __syncthreads();
    const float xn0 = Pn.x, xn1 = Pn.y, xn2 = Pn.z, q0n = Pn.w;
    float M0 = -INFINITY, M1 = -INFINITY, M2 = -INFINITY;
    float s0 = 0.f, s1 = 0.f, s2 = 0.f;
#pragma unroll 4
    for (int m = 0; m < 128; ++m) {
      float4 pm = s_p[m];
      float4 um = s_u[m];
      float dot = fmaf(xn0, pm.x, fmaf(xn1, pm.y, xn2 * pm.z));
      float C   = fmaxf((q0n + pm.w) - dot, 0.f);
      lse_up(fmaf(C, nil, um.x), M0, s0);
      lse_up(fmaf(C, nil, um.y), M1, s1);
      lse_up(fmaf(C, nil, um.z), M2, s2);
    }
    const int bn = b*N_ + n;
    g_part[(s*CH + 0)*(B_*N_) + bn] = make_float2(M0, s0);
    g_part[(s*CH + 1)*(B_*N_) + bn] = make_float2(M1, s1);
    g_part[(s*CH + 2)*(B_*N_) + bn] = make_float2(M2, s2);
  } else if (blk < 1024 + 96) {
    // ---- ab ft: one thread per (bc, n) ----
    const int blk2 = blk - 1024;
    const int bc = blk2 >> 4;             // 0..5
    const int b = bc / 3, c = bc % 3;
    const int n = ((blk2 & 15) << 8) + tid;
    if (tid < K_) {
      s_p[tid]  = g_pts[bc*K_ + tid];
      s_hk[tid] = fmaf(g_gbuf[src][bc*K_ + tid], il, LOG2E * g_blog[bc*K_ + tid]);
    }
    __syncthreads();
    float4 Pn = g_P[b*N_ + n];
    float M = -INFINITY, Ss = 0.f;
    const float q0n = Pn.w;
#pragma unroll 4
    for (int k2 = 0; k2 < K_; ++k2) {
      float4 pm = s_p[k2];
      float dot = fmaf(Pn.x, pm.x, fmaf(Pn.y, pm.y, Pn.z * pm.z));
      float C   = fmaxf((q0n + pm.w) - dot, 0.f);
      lse_up(fmaf(C, nil, s_hk[k2]), M, Ss);
    }
    float ft = -eps * LN2 * (M + flog2(Ss));
    const int o = bc*N_ + n;
    if (mode == 0) {
      g_fbuf[src ^ 1][o] = 0.5f * (g_fbuf[src][o] + ft);
    } else {
      float a = y[(size_t)(b*N_ + n) * 6 + 3 + c];
      float acc = a * ft;                 // a * F_ab
      for (int off = 32; off; off >>= 1) acc += __shfl_down(acc, off);
      if ((tid & 63) == 0) s_red[tid >> 6] = acc;
      __syncthreads();
      if (tid == 0) g_S1a[blk2] = s_red[0] + s_red[1] + s_red[2] + s_red[3];
    }
  } else {
    // ---- ab gt: one wave per (bc, k) ----
    const int blk3 = blk - 1120;
    const int wv = tid >> 6, lane = tid & 63;
    const int job = blk3 * 4 + wv;        // 0..767
    const int bc = job >> 7, k = job & (K_ - 1);
    const int b = bc / 3;
    float4 Pk = g_pts[bc*K_ + k];
    float M = -INFINITY, Ss = 0.f;
#pragma unroll 4
    for (int j = 0; j < 64; ++j) {
      int n = (j << 6) + lane;
      float4 pm = g_P[b*N_ + n];
      float f  = g_fbuf[src][bc*N_ + n];
      float al = g_alog[bc*N_ + n];
      float hn = fmaf(f, il, LOG2E * al);
      float dot = fmaf(Pk.x, pm.x, fmaf(Pk.y, pm.y, Pk.z * pm.z));
      float C   = fmaxf((Pk.w + pm.w) - dot, 0.f);
      lse_up(fmaf(C, nil, hn), M, Ss);
    }
    for (int off = 1; off < 64; off <<= 1) {
      float oM = __shfl_xor(M, off);
      float oS = __shfl_xor(Ss, off);
      lse_merge(M, Ss, oM, oS);
    }
    if (lane == 0) {
      float gt = -eps * LN2 * (M + flog2(Ss));
      const int o = bc*K_ + k;
      if (mode == 0) g_gbuf[src ^ 1][o] = 0.5f * (g_gbuf[src][o] + gt);
      else           g_Gab[job] = g_bval[o] * gt;    // b * G_ab
    }
  }
}

// ================= combine partials: thread per (c, b*N+n) =================
__global__ __launch_bounds__(256) void k_combine(float eps_cur, float eps_next, int mode) {
  const int idx = blockIdx.x * 256 + threadIdx.x;   // [0, CH*B*N)
  const int c = idx / (B_*N_);
  const int bn = idx - c*(B_*N_);
  const int b = bn >> 12, n = bn & (N_ - 1);
  float M = -INFINITY, S = 0.f;
#pragma unroll 8
  for (int s = 0; s < S_; ++s) {
    float2 p = g_part[(s*CH + c)*(B_*N_) + bn];
    lse_merge(M, S, p.x, p.y);
  }
  float sm = -eps_cur * LN2 * (M + flog2(S));
  const int o = (b*CH + c)*N_ + n;
  if (mode == 0) {
    float fn = 0.5f * (g_fa[o] + sm);
    g_fa[o] = fn;
    float U = fmaf(fn, LOG2E / eps_next, LOG2E * g_alog[o]);
    ((float*)g_U4)[bn * 4 + c] = U;
  } else {
    g_Fa[o] = sm;
  }
}

// ================= yy loop (K x K, block-local) =================
__global__ __launch_bounds__(128) void k_yy() {
  const int bc = blockIdx.x;
  const int k  = threadIdx.x;
  __shared__ float4 s_pt[K_];
  __shared__ float  s_hm[K_];
  __shared__ float  s_red[2];
  float4 Pk = g_pts[bc*K_ + k];
  s_pt[k] = Pk;
  const float blogk = g_blog[bc*K_ + k];
  const float eps_l[NEPS+1] = {4.0f, 1.0f, 0.25f, 0.0625f, 0.015625f, 0.00390625f,
                               0.0025f, 0.0025f, 0.0025f, 0.0025f, 0.0025f, 0.0025f, 0.0025f};
  float g = 0.f;
  __syncthreads();
  for (int it = 0; it <= NEPS; ++it) {
    const float eps = eps_l[it];
    const float il  = LOG2E / eps, nil = -il;
    s_hm[k] = fmaf(g, il, LOG2E * blogk);
    __syncthreads();
    float M = -INFINITY, Ss = 0.f;
    for (int m = 0; m < K_; ++m) {
      float4 pm = s_pt[m];
      float dot = fmaf(Pk.x, pm.x, fmaf(Pk.y, pm.y, Pk.z * pm.z));
      float C   = fmaxf((Pk.w + pm.w) - dot, 0.f);
      lse_up(fmaf(C, nil, s_hm[m]), M, Ss);
    }
    float sv = -eps * LN2 * (M + flog2(Ss));
    if (it < NEPS) {
      g = 0.5f * (g + sv);
      __syncthreads();
    } else {                              // G_b at eps_last
      float local = g_bval[bc*K_ + k] * sv;
      for (int off = 32; off; off >>= 1) local += __shfl_down(local, off);
      if ((threadIdx.x & 63) == 0) s_red[threadIdx.x >> 6] = local;
      __syncthreads();
      if (threadIdx.x == 0) g_S2[bc] = s_red[0] + s_red[1];
    }
  }
}

// ================= finalize =================
__global__ __launch_bounds__(1024) void k_final(const float* __restrict__ y,
                                                float* __restrict__ out) {
  const int tid = threadIdx.x;
  float local = 0.f;
  for (int i = tid; i < B_*CH*N_; i += 1024) {
    int b = i / (CH*N_); int r = i - b*CH*N_; int c = r / N_; int n = r - c*N_;
    float a = y[((size_t)(b*N_ + n)) * 6 + 3 + c];
    local -= a * g_Fa[i];
  }
  if (tid < 768) local += g_Gab[tid];
  if (tid < 96)  local += g_S1a[tid];
  if (tid < 6)   local -= g_S2[tid];
  for (int off = 32; off; off >>= 1) local += __shfl_down(local, off);
  __shared__ float s_red[16];
  if ((tid & 63) == 0) s_red[tid >> 6] = local;
  __syncthreads();
  if (tid == 0) {
    float t = 0.f;
#pragma unroll
    for (int i = 0; i < 16; ++i) t += s_red[i];
    out[0] = t;
  }
}

extern "C" void kernel_launch(void* const* d_in, const int* in_sizes, int n_in,
                              void* d_out, int out_size, void* d_ws, size_t ws_size,
                              hipStream_t stream) {
  const float* y_hat = (const float*)d_in[0];
  const float* y     = (const float*)d_in[1];
  const float* vox   = (const float*)d_in[2];
  float* out = (float*)d_out;

  static const float eps_list[NEPS] = {4.0f, 1.0f, 0.25f, 0.0625f, 0.015625f, 0.00390625f,
                                       0.0025f, 0.0025f, 0.0025f, 0.0025f, 0.0025f, 0.0025f};

  k_topk<<<6, 1024, 0, stream>>>(y_hat, vox);
  k_prep<<<(B_*N_)/256, 256, 0, stream>>>(y);
  k_yy<<<6, 128, 0, stream>>>();
  for (int it = 0; it < NEPS; ++it) {
    float eps_next = (it < NEPS - 1) ? eps_list[it + 1] : 0.0025f;
    k_pass<<<1312, 256, 0, stream>>>(eps_list[it], 0, it & 1, y);
    k_combine<<<96, 256, 0, stream>>>(eps_list[it], eps_next, 0);
  }
  k_pass<<<1312, 256, 0, stream>>>(0.0025f, 1, 0, y);
  k_combine<<<96, 256, 0, stream>>>(0.0025f, 1.0f, 1);
  k_final<<<1, 1024, 0, stream>>>(y, out);
}

// Round 3
// 359.652 us; speedup vs baseline: 8.8763x; 2.1652x over previous
//
#include <hip/hip_runtime.h>
#include <math.h>

#define B_   2
#define N_   4096
#define V_   32768
#define K_   128
#define SC   16              // m-chunks of 256 for xx
#define CH   3
#define NEPS 12
#define XXB  512             // B * 16 n-chunks * SC m-chunks
#define FTB  96
#define GTB  192
#define YYB  6
#define NBLK (XXB + FTB + GTB + YYB)   // 806

#define LOG2E 1.4426950408889634f
#define LN2   0.6931471805599453f

// ---- static device scratch ----
__device__ float4 g_P   [B_*N_];         // {x,y,z, 0.5|x|^2}
__device__ float4 g_EU4 [B_*N_];         // per-channel exp2(U - Ubar_tile)
__device__ float  g_Ubar[2][B_*SC*CH];   // per-tile anchors (double-buffered)
__device__ float  g_alog[B_*CH*N_];      // [bc][n] ln(w)
__device__ float  g_fa  [B_*CH*N_];      // sym potentials
__device__ float  g_Fa  [B_*CH*N_];      // final F_a
__device__ float  g_partS[SC*CH*B_*N_]; // partial sums (anchored at Ubar_tile)
__device__ float4 g_pts [B_*CH*K_];      // {p, 0.5|p|^2}
__device__ float  g_blog[B_*CH*K_];
__device__ float  g_bval[B_*CH*K_];
__device__ float  g_fbuf[2][B_*CH*N_];   // ping-pong f (ab)
__device__ float  g_gbuf[2][B_*CH*K_];   // ping-pong g (ab)
__device__ float  g_ybuf[2][B_*CH*K_];   // ping-pong g (yy)
__device__ float  g_S1a[FTB];            // partials of sum a*F_ab
__device__ float  g_Gab[768];            // b*G_ab per (bc,k)
__device__ float  g_S2[6];               // sum b*G_b per bc

// branchless online logsumexp update (base-2)
__device__ __forceinline__ void lse_up(float t, float& m, float& s) {
  float mn = fmaxf(m, t);
  float e  = exp2f(-fabsf(t - m));
  bool  gt = t > m;
  float mulv = gt ? e : 1.0f;
  float addv = gt ? 1.0f : e;
  s = fmaf(s, mulv, addv);
  m = mn;
}
__device__ __forceinline__ void lse_merge(float& M, float& S, float oM, float oS) {
  float mn = fmaxf(M, oM);
  float e  = exp2f(-fabsf(M - oM));
  bool  gt = oM > M;
  float sm = gt ? e : 1.0f;
  float so = gt ? 1.0f : e;
  S = fmaf(S, sm, oS * so);
  M = mn;
}

// ================= top-K (6 rows, jax.lax.top_k semantics) =================
__global__ __launch_bounds__(1024) void k_topk(const float* __restrict__ yhat,
                                               const float* __restrict__ vox) {
  const int bc  = blockIdx.x;
  const int tid = threadIdx.x;
  const float* row = yhat + (size_t)bc * V_;
  float v[32];
#pragma unroll
  for (int j = 0; j < 32; ++j) v[j] = row[tid + j * 1024];

  if (tid < K_) { g_gbuf[0][bc*K_ + tid] = 0.f; g_ybuf[0][bc*K_ + tid] = 0.f; }

  __shared__ int s_cnt;
  unsigned lo = 0u, hi = 0x3f800000u;
  while (lo < hi) {
    unsigned mid = lo + ((hi - lo + 1u) >> 1);
    if (tid == 0) s_cnt = 0;
    __syncthreads();
    int local = 0;
#pragma unroll
    for (int j = 0; j < 32; ++j) local += (__float_as_uint(v[j]) >= mid) ? 1 : 0;
    for (int off = 32; off; off >>= 1) local += __shfl_down(local, off);
    if ((tid & 63) == 0 && local) atomicAdd(&s_cnt, local);
    __syncthreads();
    int cnt = s_cnt;
    __syncthreads();
    if (cnt >= K_) lo = mid; else hi = mid - 1u;
  }
  const unsigned T = lo;

  if (tid == 0) s_cnt = 0;
  __syncthreads();
  {
    int local = 0;
#pragma unroll
    for (int j = 0; j < 32; ++j) local += (__float_as_uint(v[j]) > T) ? 1 : 0;
    for (int off = 32; off; off >>= 1) local += __shfl_down(local, off);
    if ((tid & 63) == 0 && local) atomicAdd(&s_cnt, local);
  }
  __syncthreads();
  const int c1 = s_cnt;
  __syncthreads();

  __shared__ int   s_pos, s_eq;
  __shared__ float s_vals[K_];
  __shared__ int   s_idx[K_];
  __shared__ int   s_eqi[1024];
  if (tid == 0) { s_pos = 0; s_eq = 0; }
  __syncthreads();
#pragma unroll
  for (int j = 0; j < 32; ++j) {
    unsigned bt = __float_as_uint(v[j]);
    int i = tid + j * 1024;
    if (bt > T) {
      int p = atomicAdd(&s_pos, 1);
      s_vals[p] = v[j]; s_idx[p] = i;
    } else if (bt == T) {
      int p = atomicAdd(&s_eq, 1);
      if (p < 1024) s_eqi[p] = i;
    }
  }
  __syncthreads();
  const int ec   = min(s_eq, 1024);
  const int need = K_ - c1;
  for (int e = tid; e < ec; e += 1024) {
    int my = s_eqi[e];
    int rank = 0;
    for (int j2 = 0; j2 < ec; ++j2) rank += (s_eqi[j2] < my) ? 1 : 0;
    if (rank < need) { s_vals[c1 + rank] = __uint_as_float(T); s_idx[c1 + rank] = my; }
  }
  __syncthreads();
  if (tid < K_) {
    float mv = s_vals[tid]; int mi = s_idx[tid];
    int rank = 0;
    for (int j2 = 0; j2 < K_; ++j2) {
      float ov = s_vals[j2]; int oi = s_idx[j2];
      rank += ((ov > mv) || (ov == mv && oi < mi)) ? 1 : 0;
    }
    float p0 = vox[(size_t)mi * 3 + 0];
    float p1 = vox[(size_t)mi * 3 + 1];
    float p2 = vox[(size_t)mi * 3 + 2];
    g_pts [bc * K_ + rank] = make_float4(p0, p1, p2, 0.5f * (p0*p0 + p1*p1 + p2*p2));
    g_bval[bc * K_ + rank] = mv;
    g_blog[bc * K_ + rank] = log2f(fmaxf(mv, 1e-20f)) * LN2;
  }
}

// ================= prep: P, alog, f=0, EU/Ubar for first pass =================
__global__ __launch_bounds__(256) void k_prep(const float* __restrict__ y) {
  const int tid = threadIdx.x;
  const int idx = blockIdx.x * 256 + tid;          // bn
  const int b = idx >> 12, n = idx & (N_ - 1);
  const float* yr = y + (size_t)idx * 6;
  float x0 = yr[0], x1 = yr[1], x2 = yr[2];
  g_P[idx] = make_float4(x0, x1, x2, 0.5f * (x0*x0 + x1*x1 + x2*x2));
  float U[CH];
#pragma unroll
  for (int c = 0; c < CH; ++c) {
    float w  = yr[3 + c];
    float al = log2f(fmaxf(w, 1e-20f)) * LN2;
    const int o = (b*CH + c)*N_ + n;
    g_alog[o] = al;
    g_fa  [o] = 0.f;
    g_fbuf[0][o] = 0.f;
    U[c] = LOG2E * al;                              // f=0
  }
  __shared__ float s_w[4][CH];
  float Ub[CH];
#pragma unroll
  for (int c = 0; c < CH; ++c) {
    float u = U[c];
    for (int off = 32; off; off >>= 1) u = fmaxf(u, __shfl_xor(u, off));
    if ((tid & 63) == 0) s_w[tid >> 6][c] = u;
  }
  __syncthreads();
#pragma unroll
  for (int c = 0; c < CH; ++c)
    Ub[c] = fmaxf(fmaxf(s_w[0][c], s_w[1][c]), fmaxf(s_w[2][c], s_w[3][c]));
  g_EU4[idx] = make_float4(exp2f(U[0]-Ub[0]), exp2f(U[1]-Ub[1]), exp2f(U[2]-Ub[2]), 0.f);
  if (tid == 0) {
    const int tile = blockIdx.x;                    // = bn>>8
#pragma unroll
    for (int c = 0; c < CH; ++c) g_Ubar[0][tile*CH + c] = Ub[c];
  }
}

// ======== fused pass: xx(512) + ab-ft(96) + ab-gt(192) + yy(6) ========
__global__ __launch_bounds__(256) void k_pass(float eps, int mode, int src,
                                              const float* __restrict__ y) {
  const float il = LOG2E / eps, nil = -il;
  const int blk = blockIdx.x, tid = threadIdx.x;
  __shared__ float4 s_A[256];
  __shared__ float4 s_B[256];
  __shared__ float  s_C[256];
  __shared__ float  s_D[256];
  __shared__ float  s_w[4];

  if (blk < XXB) {
    // ---- xx: factored-exp partial sums, 256 n x 256 m ----
    const int s  = blk & (SC - 1);
    const int nb = blk >> 4;           // 0..31
    const int b  = nb >> 4;
    const int n  = ((nb & 15) << 8) + tid;
    const int m0 = s << 8;
    s_A[tid] = g_P  [b*N_ + m0 + tid];
    s_B[tid] = g_EU4[b*N_ + m0 + tid];
    float4 Pn = g_P[b*N_ + n];
    __syncthreads();
    float S0=0.f,S1=0.f,S2v=0.f,T0=0.f,T1=0.f,T2=0.f;
#pragma unroll 4
    for (int m = 0; m < 256; m += 2) {
      float4 p1 = s_A[m];     float4 u1 = s_B[m];
      float4 p2 = s_A[m+1];   float4 u2 = s_B[m+1];
      float d1 = fmaf(Pn.x, p1.x, fmaf(Pn.y, p1.y, Pn.z * p1.z));
      float C1 = fmaxf((Pn.w + p1.w) - d1, 0.f);
      float e1 = exp2f(C1 * nil);
      S0 = fmaf(u1.x, e1, S0); S1 = fmaf(u1.y, e1, S1); S2v = fmaf(u1.z, e1, S2v);
      float d2 = fmaf(Pn.x, p2.x, fmaf(Pn.y, p2.y, Pn.z * p2.z));
      float C2 = fmaxf((Pn.w + p2.w) - d2, 0.f);
      float e2 = exp2f(C2 * nil);
      T0 = fmaf(u2.x, e2, T0); T1 = fmaf(u2.y, e2, T1); T2 = fmaf(u2.z, e2, T2);
    }
    const int bn = b*N_ + n;
    g_partS[(s*CH + 0)*(B_*N_) + bn] = S0 + T0;
    g_partS[(s*CH + 1)*(B_*N_) + bn] = S1 + T1;
    g_partS[(s*CH + 2)*(B_*N_) + bn] = S2v + T2;
  } else if (blk < XXB + FTB) {
    // ---- ab ft: factored exp over k, with underflow fallback ----
    const int blk2 = blk - XXB;
    const int bc = blk2 >> 4;
    const int b = bc / 3, c = bc % 3;
    const int n = ((blk2 & 15) << 8) + tid;
    float Hk = -INFINITY;
    if (tid < K_) {
      float g = g_gbuf[src][bc*K_ + tid];
      Hk = fmaf(g, il, LOG2E * g_blog[bc*K_ + tid]);
      s_A[tid] = g_pts[bc*K_ + tid];
    }
    float hm = Hk;
    for (int off = 32; off; off >>= 1) hm = fmaxf(hm, __shfl_xor(hm, off));
    if ((tid & 63) == 0) s_w[tid >> 6] = hm;
    __syncthreads();
    const float Hbar = fmaxf(fmaxf(s_w[0], s_w[1]), fmaxf(s_w[2], s_w[3]));
    if (tid < K_) { float dh = Hk - Hbar; s_C[tid] = exp2f(dh); s_D[tid] = dh; }
    float4 Pn = g_P[b*N_ + n];
    __syncthreads();
    float S = 0.f, T = 0.f, M = -INFINITY;
#pragma unroll 4
    for (int k2 = 0; k2 < K_; k2 += 2) {
      float4 p1 = s_A[k2];
      float d1 = fmaf(Pn.x, p1.x, fmaf(Pn.y, p1.y, Pn.z * p1.z));
      float C1 = fmaxf((Pn.w + p1.w) - d1, 0.f);
      float w1 = C1 * nil;
      S = fmaf(s_C[k2], exp2f(w1), S);
      M = fmaxf(M, w1 + s_D[k2]);
      float4 p2 = s_A[k2+1];
      float d2 = fmaf(Pn.x, p2.x, fmaf(Pn.y, p2.y, Pn.z * p2.z));
      float C2 = fmaxf((Pn.w + p2.w) - d2, 0.f);
      float w2 = C2 * nil;
      T = fmaf(s_C[k2+1], exp2f(w2), T);
      M = fmaxf(M, w2 + s_D[k2+1]);
    }
    S += T;
    float lse = (S > 0.f) ? log2f(S) : M;      // fallback if all terms underflow
    float ft = -eps * LN2 * (Hbar + lse);
    if (mode == 0) {
      g_fbuf[src ^ 1][bc*N_ + n] = 0.5f * (g_fbuf[src][bc*N_ + n] + ft);
    } else {
      float a = y[(size_t)(b*N_ + n) * 6 + 3 + c];
      float acc = a * ft;
      for (int off = 32; off; off >>= 1) acc += __shfl_down(acc, off);
      __syncthreads();
      if ((tid & 63) == 0) s_w[tid >> 6] = acc;
      __syncthreads();
      if (tid == 0) g_S1a[blk2] = s_w[0] + s_w[1] + s_w[2] + s_w[3];
    }
  } else if (blk < XXB + FTB + GTB) {
    // ---- ab gt: one wave per (bc,k), online LSE over n ----
    const int job = (blk - (XXB + FTB)) * 4 + (tid >> 6);
    const int bc = job >> 7, k = job & (K_ - 1);
    const int b = bc / 3;
    const int lane = tid & 63;
    float4 Pk = g_pts[bc*K_ + k];
    float M0 = -INFINITY, S0 = 0.f, M1 = -INFINITY, S1 = 0.f;
#pragma unroll 2
    for (int j = 0; j < 64; j += 2) {
      {
        int n = (j << 6) + lane;
        float4 pm = g_P[b*N_ + n];
        float f  = g_fbuf[src][bc*N_ + n];
        float al = g_alog[bc*N_ + n];
        float Hn = fmaf(f, il, LOG2E * al);
        float d = fmaf(Pk.x, pm.x, fmaf(Pk.y, pm.y, Pk.z * pm.z));
        float C = fmaxf((Pk.w + pm.w) - d, 0.f);
        lse_up(fmaf(C, nil, Hn), M0, S0);
      }
      {
        int n = ((j+1) << 6) + lane;
        float4 pm = g_P[b*N_ + n];
        float f  = g_fbuf[src][bc*N_ + n];
        float al = g_alog[bc*N_ + n];
        float Hn = fmaf(f, il, LOG2E * al);
        float d = fmaf(Pk.x, pm.x, fmaf(Pk.y, pm.y, Pk.z * pm.z));
        float C = fmaxf((Pk.w + pm.w) - d, 0.f);
        lse_up(fmaf(C, nil, Hn), M1, S1);
      }
    }
    lse_merge(M0, S0, M1, S1);
    for (int off = 1; off < 64; off <<= 1) {
      float oM = __shfl_xor(M0, off);
      float oS = __shfl_xor(S0, off);
      lse_merge(M0, S0, oM, oS);
    }
    if (lane == 0) {
      float gt = -eps * LN2 * (M0 + log2f(S0));
      const int o = bc*K_ + k;
      if (mode == 0) g_gbuf[src ^ 1][o] = 0.5f * (g_gbuf[src][o] + gt);
      else           g_Gab[job] = g_bval[o] * gt;
    }
  } else {
    // ---- yy: one iteration of the K x K sym loop ----
    const int bc = blk - (XXB + FTB + GTB);
    const int k = tid & (K_ - 1);
    if (tid < K_) {
      s_A[tid] = g_pts[bc*K_ + tid];
      float g = g_ybuf[src][bc*K_ + tid];
      s_C[tid] = fmaf(g, il, LOG2E * g_blog[bc*K_ + tid]);
      s_D[tid] = g;
    }
    __syncthreads();
    float4 Pk = s_A[k];
    float M = -INFINITY, S = 0.f;
    for (int m = 0; m < K_; ++m) {
      float4 pm = s_A[m];
      float d = fmaf(Pk.x, pm.x, fmaf(Pk.y, pm.y, Pk.z * pm.z));
      float C = fmaxf((Pk.w + pm.w) - d, 0.f);
      lse_up(fmaf(C, nil, s_C[m]), M, S);
    }
    float sv = -eps * LN2 * (M + log2f(S));
    if (mode == 0) {
      if (tid < K_) g_ybuf[src ^ 1][bc*K_ + k] = 0.5f * (s_D[k] + sv);
    } else {
      float val = (tid < K_) ? g_bval[bc*K_ + k] * sv : 0.f;
      for (int off = 32; off; off >>= 1) val += __shfl_down(val, off);
      __syncthreads();
      if ((tid & 63) == 0) s_w[tid >> 6] = val;
      __syncthreads();
      if (tid == 0) g_S2[bc] = s_w[0] + s_w[1] + s_w[2] + s_w[3];
    }
  }
}

// ================= combine: merge 16 anchored partials, emit next EU/Ubar =================
__global__ __launch_bounds__(256) void k_combine(float eps_cur, float eps_next,
                                                 int mode, int ubsrc) {
  const int tid = threadIdx.x;
  const int idx = blockIdx.x * 256 + tid;          // [0, CH*B*N)
  const int c  = idx >> 13;
  const int bn = idx & (B_*N_ - 1);
  const int b = bn >> 12, n = bn & (N_ - 1);
  const int tile = bn >> 8;
  __shared__ float s_scale[SC];
  __shared__ float s_mm;
  __shared__ float s_w[4];
  const int tb = b * SC;
  if (tid < SC) s_scale[tid] = g_Ubar[ubsrc][(tb + tid)*CH + c];
  __syncthreads();
  if (tid == 0) {
    float mm = s_scale[0];
#pragma unroll
    for (int s = 1; s < SC; ++s) mm = fmaxf(mm, s_scale[s]);
    s_mm = mm;
  }
  __syncthreads();
  const float Mmax = s_mm;
  if (tid < SC) s_scale[tid] = exp2f(s_scale[tid] - Mmax);
  __syncthreads();
  float S = 0.f;
#pragma unroll
  for (int s = 0; s < SC; ++s)
    S = fmaf(g_partS[(s*CH + c)*(B_*N_) + bn], s_scale[s], S);
  float sm = -eps_cur * LN2 * (Mmax + log2f(S));
  const int o = (b*CH + c)*N_ + n;
  if (mode == 0) {
    float fn = 0.5f * (g_fa[o] + sm);
    g_fa[o] = fn;
    float U = fmaf(fn, LOG2E / eps_next, LOG2E * g_alog[o]);
    float u = U;
    for (int off = 32; off; off >>= 1) u = fmaxf(u, __shfl_xor(u, off));
    if ((tid & 63) == 0) s_w[tid >> 6] = u;
    __syncthreads();
    float Ub = fmaxf(fmaxf(s_w[0], s_w[1]), fmaxf(s_w[2], s_w[3]));
    ((float*)g_EU4)[bn * 4 + c] = exp2f(U - Ub);
    if (tid == 0) g_Ubar[ubsrc ^ 1][tile*CH + c] = Ub;
  } else {
    g_Fa[o] = sm;
  }
}

// ================= finalize =================
__global__ __launch_bounds__(1024) void k_final(const float* __restrict__ y,
                                                float* __restrict__ out) {
  const int tid = threadIdx.x;
  float local = 0.f;
  for (int i = tid; i < B_*CH*N_; i += 1024) {
    int b = i / (CH*N_); int r = i - b*CH*N_; int c = r / N_; int n = r - c*N_;
    float a = y[((size_t)(b*N_ + n)) * 6 + 3 + c];
    local -= a * g_Fa[i];
  }
  if (tid < 768) local += g_Gab[tid];
  if (tid < 96)  local += g_S1a[tid];
  if (tid < 6)   local -= g_S2[tid];
  for (int off = 32; off; off >>= 1) local += __shfl_down(local, off);
  __shared__ float s_red[16];
  if ((tid & 63) == 0) s_red[tid >> 6] = local;
  __syncthreads();
  if (tid == 0) {
    float t = 0.f;
#pragma unroll
    for (int i = 0; i < 16; ++i) t += s_red[i];
    out[0] = t;
  }
}

extern "C" void kernel_launch(void* const* d_in, const int* in_sizes, int n_in,
                              void* d_out, int out_size, void* d_ws, size_t ws_size,
                              hipStream_t stream) {
  const float* y_hat = (const float*)d_in[0];
  const float* y     = (const float*)d_in[1];
  const float* vox   = (const float*)d_in[2];
  float* out = (float*)d_out;

  static const float eps_list[NEPS] = {4.0f, 1.0f, 0.25f, 0.0625f, 0.015625f, 0.00390625f,
                                       0.0025f, 0.0025f, 0.0025f, 0.0025f, 0.0025f, 0.0025f};

  k_topk<<<6, 1024, 0, stream>>>(y_hat, vox);
  k_prep<<<(B_*N_)/256, 256, 0, stream>>>(y);
  for (int it = 0; it < NEPS; ++it) {
    float eps_next = (it < NEPS - 1) ? eps_list[it + 1] : 0.0025f;
    k_pass<<<NBLK, 256, 0, stream>>>(eps_list[it], 0, it & 1, y);
    k_combine<<<96, 256, 0, stream>>>(eps_list[it], eps_next, 0, it & 1);
  }
  k_pass<<<NBLK, 256, 0, stream>>>(0.0025f, 1, 0, y);
  k_combine<<<96, 256, 0, stream>>>(0.0025f, 1.0f, 1, 0);
  k_final<<<1, 1024, 0, stream>>>(y, out);
}